// Round 6
// baseline (28695.679 us; speedup 1.0000x reference)
//
#include <hip/hip_runtime.h>
#include <hip/hip_bf16.h>
#include <hip/hip_fp16.h>

// Problem constants
#define NB 256   // batch
#define NH 512   // hidden
#define NL 3     // lstm layers
#define NT 200   // time steps
#define NV 100   // vocab
#define NVP 112  // vocab padded to 7*16
#define NG 2048  // 4*NH gates
#define NK 1024  // 2*NH (x|h concat K)

using f16x8 = __attribute__((ext_vector_type(8))) _Float16;
using f32x4 = __attribute__((ext_vector_type(4))) float;

__device__ __forceinline__ float sigf(float x) { return 1.f / (1.f + __expf(-x)); }
__device__ __forceinline__ float tanhf_(float x) { return 2.f / (1.f + __expf(-2.f * x)) - 1.f; }

// ---------------- grid barrier (all blocks co-resident; device-scope) ----------------
__device__ __forceinline__ void gbar(int* bar, int& phase) {
  __threadfence();
  __syncthreads();
  if (threadIdx.x == 0) {
    __hip_atomic_fetch_add(bar, 1, __ATOMIC_RELEASE, __HIP_MEMORY_SCOPE_AGENT);
    ++phase;
    const int tgt = phase * (int)gridDim.x;
    while (__hip_atomic_load(bar, __ATOMIC_RELAXED, __HIP_MEMORY_SCOPE_AGENT) < tgt)
      __builtin_amdgcn_s_sleep(2);
    (void)__hip_atomic_load(bar, __ATOMIC_ACQUIRE, __HIP_MEMORY_SCOPE_AGENT);
  }
  __syncthreads();
}

// ---------------- MFMA layout probe ----------------
__global__ void k_probe(int* __restrict__ rowmap, int* __restrict__ colmap) {
  const int lane = threadIdx.x & 63;
  f16x8 a, b;
  const _Float16 idv = (_Float16)(float)(lane & 15);
  const _Float16 inv = (_Float16)(1.f / 32.f);
#pragma unroll
  for (int j = 0; j < 8; ++j) { a[j] = idv; b[j] = inv; }
  f32x4 d = {0.f, 0.f, 0.f, 0.f};
  d = __builtin_amdgcn_mfma_f32_16x16x32_f16(a, b, d, 0, 0, 0);
#pragma unroll
  for (int r = 0; r < 4; ++r) rowmap[lane * 4 + r] = (int)(d[r] + 0.5f);
#pragma unroll
  for (int j = 0; j < 8; ++j) { a[j] = inv; b[j] = idv; }
  f32x4 e = {0.f, 0.f, 0.f, 0.f};
  e = __builtin_amdgcn_mfma_f32_16x16x32_f16(a, b, e, 0, 0, 0);
#pragma unroll
  for (int r = 0; r < 4; ++r) colmap[lane * 4 + r] = (int)(e[r] + 0.5f);
}

// ---------------- prep: permute+convert recurrent weights to fp16 ----------------
// W[l][r][k], r = hu*4+g; k<512 -> w_ih, k>=512 -> w_hh. bias[l][r] = b_ih + b_hh.
__global__ void k_prep_w(const float* __restrict__ w_ih, const float* __restrict__ w_hh,
                         const float* __restrict__ b_ih, const float* __restrict__ b_hh,
                         _Float16* __restrict__ W, float* __restrict__ bias) {
  const int stride = gridDim.x * blockDim.x;
  const int tid0 = blockIdx.x * blockDim.x + threadIdx.x;
  for (int idx = tid0; idx < NL * NG * NK; idx += stride) {
    const int k = idx & (NK - 1);
    const int r = (idx >> 10) & (NG - 1);
    const int l = idx >> 21;
    const int hu = r >> 2, g = r & 3;
    const int srow = l * NG + g * NH + hu;
    const float v = (k < NH) ? w_ih[(size_t)srow * NH + k]
                             : w_hh[(size_t)srow * NH + (k - NH)];
    W[idx] = (_Float16)v;
  }
  for (int idx = tid0; idx < NL * NG; idx += stride) {
    const int r = idx & (NG - 1);
    const int l = idx >> 11;
    const int hu = r >> 2, g = r & 3;
    const int srow = l * NG + g * NH + hu;
    bias[idx] = b_ih[srow] + b_hh[srow];
  }
}

// ---------------- prep: x0, projection weights, barrier reset ----------------
__global__ void k_prep_misc(const float* __restrict__ embed, const int* __restrict__ start_idx,
                            const float* __restrict__ w1, const float* __restrict__ b1,
                            const float* __restrict__ w2, const float* __restrict__ b2,
                            _Float16* __restrict__ x0, _Float16* __restrict__ pw1, float* __restrict__ pb1,
                            _Float16* __restrict__ pw2, float* __restrict__ pb2, int* __restrict__ bar) {
  const int stride = gridDim.x * blockDim.x;
  const int tid0 = blockIdx.x * blockDim.x + threadIdx.x;
  if (tid0 == 0) bar[0] = 0;
  const int st = start_idx[0];
  for (int i = tid0; i < NB * NH; i += stride)
    x0[i] = (_Float16)embed[(size_t)st * NH + (i & (NH - 1))];
  for (int i = tid0; i < 2 * NH * NH; i += stride)
    pw1[i] = (_Float16)w1[i];
  for (int i = tid0; i < NVP * NK; i += stride) {
    const int r = i >> 10;
    pw2[i] = (_Float16)((r < NV) ? w2[i] : 0.f);
  }
  for (int i = tid0; i < 2 * NH; i += stride) pb1[i] = b1[i];
  for (int i = tid0; i < NVP; i += stride) pb2[i] = (i < NV) ? b2[i] : 0.f;
}

// ---------------- visual GEMV: out[b][j] = dot(x[b,:], w[j,:]) + bias[j] (f32) ----------------
__global__ void k_gemv512(const float* __restrict__ x, const float* __restrict__ w,
                          const float* __restrict__ bias, float* __restrict__ out) {
  const int b = blockIdx.x;
  __shared__ float xs[NH];
  for (int i = threadIdx.x; i < NH; i += 256) xs[i] = x[(size_t)b * NH + i];
  __syncthreads();
  const int wave = threadIdx.x >> 6, lane = threadIdx.x & 63;
  for (int j = wave; j < NH; j += 4) {
    const float* wr = w + (size_t)j * NH;
    float s = 0.f;
#pragma unroll
    for (int i = 0; i < 8; ++i) s += wr[lane + i * 64] * xs[lane + i * 64];
#pragma unroll
    for (int o = 32; o > 0; o >>= 1) s += __shfl_down(s, o);
    if (lane == 0) out[(size_t)b * NH + j] = s + bias[j];
  }
}

// second visual GEMV + broadcast h0 into all layers (parity 0) + zero c
__global__ void k_gemv2_init(const float* __restrict__ feat1, const float* __restrict__ w,
                             const float* __restrict__ bias, _Float16* __restrict__ hbuf,
                             float* __restrict__ cbuf) {
  const int b = blockIdx.x;
  __shared__ float xs[NH];
  for (int i = threadIdx.x; i < NH; i += 256) xs[i] = feat1[(size_t)b * NH + i];
  __syncthreads();
  const int wave = threadIdx.x >> 6, lane = threadIdx.x & 63;
  for (int j = wave; j < NH; j += 4) {
    const float* wr = w + (size_t)j * NH;
    float s = 0.f;
#pragma unroll
    for (int i = 0; i < 8; ++i) s += wr[lane + i * 64] * xs[lane + i * 64];
#pragma unroll
    for (int o = 32; o > 0; o >>= 1) s += __shfl_down(s, o);
    if (lane == 0) {
      const float hv = s + bias[j];
      const _Float16 h16 = (_Float16)hv;
#pragma unroll
      for (int l = 0; l < NL; ++l) {
        hbuf[((size_t)(l * 2 + 0) * NB + b) * NH + j] = h16;  // parity 0
        cbuf[((size_t)l * NB + b) * NH + j] = 0.f;
      }
    }
  }
}

// ---------------- persistent LSTM recurrence ----------------
// grid = 256 blocks (8 batch-slices x 32 gate-slices), 4 waves/block.
__global__ __launch_bounds__(256) void k_lstm(const _Float16* __restrict__ W, const float* __restrict__ bias,
                                              _Float16* __restrict__ hbuf, float* __restrict__ cbuf,
                                              const _Float16* __restrict__ x0, _Float16* __restrict__ outs,
                                              const int* __restrict__ rowmap, const int* __restrict__ colmap,
                                              int* __restrict__ bar) {
  const int tid = threadIdx.x;
  const int lane = tid & 63;
  const int wave = tid >> 6;
  const int bm = blockIdx.x & 7;    // batch slice (32 rows)
  const int bn = blockIdx.x >> 3;   // gate slice (64 permuted rows = 16 hidden units)
  const int wm = wave & 1;
  const int wn = wave >> 1;
  const int lr = lane & 15;
  const int lh = lane >> 4;
  const int m0 = bm * 32 + wm * 16;
  const int aoff = (m0 + lr) * NH + lh * 8;
  const int nb0 = bn * 64 + wn * 32;
  const size_t boff0 = (size_t)(nb0 + lr) * NK + lh * 8;
  const size_t boff1 = (size_t)(nb0 + 16 + lr) * NK + lh * 8;
  __shared__ float gl[32][68];
  int phase = 0;

  int rm[4], cm[4];
#pragma unroll
  for (int r = 0; r < 4; ++r) {
    rm[r] = rowmap[lane * 4 + r];
    cm[r] = colmap[lane * 4 + r];
  }
  float bsv[2][NL][4];
#pragma unroll
  for (int rep = 0; rep < 2; ++rep) {
    const int item = tid + rep * 256;
    const int hu = item & 15;
    const int hg = bn * 16 + hu;
#pragma unroll
    for (int l = 0; l < NL; ++l)
#pragma unroll
      for (int g = 0; g < 4; ++g) bsv[rep][l][g] = bias[l * NG + hg * 4 + g];
  }

#pragma unroll 1
  for (int t = 0; t < NT; ++t) {
    const int p = t & 1;
#pragma unroll 1
    for (int l = 0; l < NL; ++l) {
      const _Float16* xin = (l == 0) ? ((t == 0) ? x0 : hbuf + (size_t)(2 * 2 + p) * NB * NH)
                                     : hbuf + (size_t)((l - 1) * 2 + (p ^ 1)) * NB * NH;
      const _Float16* hprev = hbuf + (size_t)(l * 2 + p) * NB * NH;
      const _Float16* Wl = W + (size_t)l * NG * NK;
      f32x4 acc0 = {0.f, 0.f, 0.f, 0.f};
      f32x4 acc1 = {0.f, 0.f, 0.f, 0.f};
#pragma unroll 4
      for (int kk = 0; kk < 32; ++kk) {
        const _Float16* Ap = (kk < 16) ? xin : hprev;
        const int ko = (kk & 15) * 32;
        f16x8 av = *(const f16x8*)(Ap + aoff + ko);
        f16x8 b0 = *(const f16x8*)(Wl + boff0 + (size_t)kk * 32);
        f16x8 b1 = *(const f16x8*)(Wl + boff1 + (size_t)kk * 32);
        acc0 = __builtin_amdgcn_mfma_f32_16x16x32_f16(av, b0, acc0, 0, 0, 0);
        acc1 = __builtin_amdgcn_mfma_f32_16x16x32_f16(av, b1, acc1, 0, 0, 0);
      }
#pragma unroll
      for (int r = 0; r < 4; ++r) {
        gl[wm * 16 + rm[r]][wn * 32 + cm[r]] = acc0[r];
        gl[wm * 16 + rm[r]][wn * 32 + 16 + cm[r]] = acc1[r];
      }
      __syncthreads();
      _Float16* hnew = hbuf + (size_t)(l * 2 + (p ^ 1)) * NB * NH;
#pragma unroll
      for (int rep = 0; rep < 2; ++rep) {
        const int item = tid + rep * 256;
        const int bl_ = item >> 4;
        const int hu = item & 15;
        const float gi = gl[bl_][hu * 4 + 0] + bsv[rep][l][0];
        const float gf = gl[bl_][hu * 4 + 1] + bsv[rep][l][1];
        const float gg = gl[bl_][hu * 4 + 2] + bsv[rep][l][2];
        const float go = gl[bl_][hu * 4 + 3] + bsv[rep][l][3];
        const int bg = bm * 32 + bl_;
        const int hg = bn * 16 + hu;
        float* cp = cbuf + ((size_t)l * NB + bg) * NH + hg;
        const float cold = *cp;
        const float cn = sigf(gf) * cold + sigf(gi) * tanhf_(gg);
        const float hn = sigf(go) * tanhf_(cn);
        *cp = cn;
        const _Float16 hv = (_Float16)hn;
        hnew[(size_t)bg * NH + hg] = hv;
        if (l == 2) outs[((size_t)t * NB + bg) * NH + hg] = hv;
      }
      gbar(bar, phase);
    }
  }
}

// ---------------- projection head: gelu(res@W1^T+b1)@W2^T+b2 -> out[b][v][t] (f32!) ----------------
__global__ __launch_bounds__(256) void k_proj(const _Float16* __restrict__ outs, const _Float16* __restrict__ pw1,
                                              const float* __restrict__ pb1, const _Float16* __restrict__ pw2,
                                              const float* __restrict__ pb2,
                                              const int* __restrict__ rowmap, const int* __restrict__ colmap,
                                              float* __restrict__ out) {
  const int tid = threadIdx.x;
  const int lane = tid & 63;
  const int wave = tid >> 6;
  const int lr = lane & 15;
  const int lh = lane >> 4;
  const int mbase = blockIdx.x * 16;
  __shared__ _Float16 hm[16][NK + 8];
  int rm[4], cm[4];
#pragma unroll
  for (int r = 0; r < 4; ++r) {
    rm[r] = rowmap[lane * 4 + r];
    cm[r] = colmap[lane * 4 + r];
  }
  const int mrow = mbase + lr;
  const _Float16* ap = outs + ((size_t)(mrow % NT) * NB + (mrow / NT)) * NH + lh * 8;
  // phase 1: hmid[16][1024]
  for (int nf = 0; nf < 16; ++nf) {
    const int n0 = wave * 256 + nf * 16;
    f32x4 acc = {0.f, 0.f, 0.f, 0.f};
    const _Float16* bp = pw1 + (size_t)(n0 + lr) * NH + lh * 8;
#pragma unroll 4
    for (int kk = 0; kk < 16; ++kk) {
      f16x8 a = *(const f16x8*)(ap + kk * 32);
      f16x8 b = *(const f16x8*)(bp + kk * 32);
      acc = __builtin_amdgcn_mfma_f32_16x16x32_f16(a, b, acc, 0, 0, 0);
    }
#pragma unroll
    for (int r = 0; r < 4; ++r) {
      const float v = acc[r] + pb1[n0 + cm[r]];
      const float gv = 0.5f * v * (1.f + erff(v * 0.70710678118654752f));
      hm[rm[r]][n0 + cm[r]] = (_Float16)gv;
    }
  }
  __syncthreads();
  // phase 2: logits[16][112], K=1024 from LDS
  for (int nf = wave; nf < 7; nf += 4) {
    const int n0 = nf * 16;
    f32x4 acc = {0.f, 0.f, 0.f, 0.f};
    const _Float16* bp = pw2 + (size_t)(n0 + lr) * NK + lh * 8;
#pragma unroll 4
    for (int kk = 0; kk < 32; ++kk) {
      f16x8 a = *(const f16x8*)(&hm[lr][kk * 32 + lh * 8]);
      f16x8 b = *(const f16x8*)(bp + kk * 32);
      acc = __builtin_amdgcn_mfma_f32_16x16x32_f16(a, b, acc, 0, 0, 0);
    }
#pragma unroll
    for (int r = 0; r < 4; ++r) {
      const int v = n0 + cm[r];
      if (v < NV) {
        const int m = mbase + rm[r];
        out[((size_t)(m / NT) * NV + v) * NT + (m % NT)] = acc[r] + pb2[v];  // f32 store
      }
    }
  }
}

extern "C" void kernel_launch(void* const* d_in, const int* in_sizes, int n_in,
                              void* d_out, int out_size, void* d_ws, size_t ws_size,
                              hipStream_t stream) {
  const float* feat = (const float*)d_in[0];
  const float* visual_w = (const float*)d_in[1];
  const float* visual_b = (const float*)d_in[2];
  const float* embed = (const float*)d_in[3];
  const float* w_ih = (const float*)d_in[4];
  const float* w_hh = (const float*)d_in[5];
  const float* b_ih = (const float*)d_in[6];
  const float* b_hh = (const float*)d_in[7];
  const float* proj_w1 = (const float*)d_in[8];
  const float* proj_b1 = (const float*)d_in[9];
  const float* proj_w2 = (const float*)d_in[10];
  const float* proj_b2 = (const float*)d_in[11];
  const int* start_idx = (const int*)d_in[12];
  float* out = (float*)d_out;  // reference output dtype is float32

  char* ws = (char*)d_ws;
  size_t off = 0;
  auto alloc = [&](size_t bytes) -> void* {
    void* p = ws + off;
    off += (bytes + 255) & ~(size_t)255;
    return p;
  };
  _Float16* W = (_Float16*)alloc((size_t)NL * NG * NK * 2);
  float* bias = (float*)alloc((size_t)NL * NG * 4);
  _Float16* hbuf = (_Float16*)alloc((size_t)6 * NB * NH * 2);  // [l][parity][B][H]
  float* cbuf = (float*)alloc((size_t)NL * NB * NH * 4);
  _Float16* x0 = (_Float16*)alloc((size_t)NB * NH * 2);
  _Float16* outsb = (_Float16*)alloc((size_t)NT * NB * NH * 2);
  float* feat1 = (float*)alloc((size_t)NB * NH * 4);
  _Float16* pw1 = (_Float16*)alloc((size_t)2 * NH * NH * 2);
  _Float16* pw2 = (_Float16*)alloc((size_t)NVP * NK * 2);
  float* pb1 = (float*)alloc((size_t)2 * NH * 4);
  float* pb2 = (float*)alloc((size_t)NVP * 4);
  int* bar = (int*)alloc(256);
  int* rowmap = (int*)alloc(256 * 4);
  int* colmap = (int*)alloc(256 * 4);
  if (off > ws_size) return;  // insufficient workspace — fail visibly

  k_probe<<<dim3(1), dim3(64), 0, stream>>>(rowmap, colmap);
  k_prep_w<<<dim3(2048), dim3(256), 0, stream>>>(w_ih, w_hh, b_ih, b_hh, W, bias);
  k_prep_misc<<<dim3(1024), dim3(256), 0, stream>>>(embed, start_idx, proj_w1, proj_b1, proj_w2, proj_b2,
                                                    x0, pw1, pb1, pw2, pb2, bar);
  k_gemv512<<<dim3(NB), dim3(256), 0, stream>>>(feat, visual_w, visual_b, feat1);
  k_gemv2_init<<<dim3(NB), dim3(256), 0, stream>>>(feat1, visual_w, visual_b, hbuf, cbuf);
  k_lstm<<<dim3(256), dim3(256), 0, stream>>>(W, bias, hbuf, cbuf, x0, outsb, rowmap, colmap, bar);
  k_proj<<<dim3(3200), dim3(256), 0, stream>>>(outsb, pw1, pb1, pw2, pb2, rowmap, colmap, out);
}

// Round 7
// 26208.859 us; speedup vs baseline: 1.0949x; 1.0949x over previous
//
#include <hip/hip_runtime.h>
#include <hip/hip_bf16.h>
#include <hip/hip_fp16.h>

// Problem constants
#define NB 256   // batch
#define NH 512   // hidden
#define NL 3     // lstm layers
#define NT 200   // time steps
#define NV 100   // vocab
#define NVP 112  // vocab padded to 7*16
#define NG 2048  // 4*NH gates
#define NK 1024  // 2*NH (x|h concat K)

using f16x8 = __attribute__((ext_vector_type(8))) _Float16;
using f32x4 = __attribute__((ext_vector_type(4))) float;

__device__ __forceinline__ float sigf(float x) { return 1.f / (1.f + __expf(-x)); }
__device__ __forceinline__ float tanhf_(float x) { return 2.f / (1.f + __expf(-2.f * x)) - 1.f; }

// ---------------- per-group flag barrier (32 blocks / group, no atomic RMW) ----------------
// flags[slot*16]: slot = group*32 + j. Each block release-stores its phase; 32 lanes poll.
__device__ __forceinline__ void group_bar(int* flags, int gbase, int myslot, int tid, int target) {
  __threadfence();
  __syncthreads();
  if (tid == 0)
    __hip_atomic_store(&flags[(gbase + myslot) * 16], target, __ATOMIC_RELEASE, __HIP_MEMORY_SCOPE_AGENT);
  if (tid < 32) {
    const int* fp = &flags[(gbase + tid) * 16];
    while (__hip_atomic_load(fp, __ATOMIC_ACQUIRE, __HIP_MEMORY_SCOPE_AGENT) < target)
      __builtin_amdgcn_s_sleep(1);
  }
  __syncthreads();
}

// ---------------- MFMA layout probe ----------------
__global__ void k_probe(int* __restrict__ rowmap, int* __restrict__ colmap) {
  const int lane = threadIdx.x & 63;
  f16x8 a, b;
  const _Float16 idv = (_Float16)(float)(lane & 15);
  const _Float16 inv = (_Float16)(1.f / 32.f);
#pragma unroll
  for (int j = 0; j < 8; ++j) { a[j] = idv; b[j] = inv; }
  f32x4 d = {0.f, 0.f, 0.f, 0.f};
  d = __builtin_amdgcn_mfma_f32_16x16x32_f16(a, b, d, 0, 0, 0);
#pragma unroll
  for (int r = 0; r < 4; ++r) rowmap[lane * 4 + r] = (int)(d[r] + 0.5f);
#pragma unroll
  for (int j = 0; j < 8; ++j) { a[j] = inv; b[j] = idv; }
  f32x4 e = {0.f, 0.f, 0.f, 0.f};
  e = __builtin_amdgcn_mfma_f32_16x16x32_f16(a, b, e, 0, 0, 0);
#pragma unroll
  for (int r = 0; r < 4; ++r) colmap[lane * 4 + r] = (int)(e[r] + 0.5f);
}

// ---------------- prep: permute+convert recurrent weights to fp16 ----------------
// W[l][r][k], r = hu*4+g; k<512 -> w_ih, k>=512 -> w_hh. bias[l][r] = b_ih + b_hh.
__global__ void k_prep_w(const float* __restrict__ w_ih, const float* __restrict__ w_hh,
                         const float* __restrict__ b_ih, const float* __restrict__ b_hh,
                         _Float16* __restrict__ W, float* __restrict__ bias) {
  const int stride = gridDim.x * blockDim.x;
  const int tid0 = blockIdx.x * blockDim.x + threadIdx.x;
  for (int idx = tid0; idx < NL * NG * NK; idx += stride) {
    const int k = idx & (NK - 1);
    const int r = (idx >> 10) & (NG - 1);
    const int l = idx >> 21;
    const int hu = r >> 2, g = r & 3;
    const int srow = l * NG + g * NH + hu;
    const float v = (k < NH) ? w_ih[(size_t)srow * NH + k]
                             : w_hh[(size_t)srow * NH + (k - NH)];
    W[idx] = (_Float16)v;
  }
  for (int idx = tid0; idx < NL * NG; idx += stride) {
    const int r = idx & (NG - 1);
    const int l = idx >> 11;
    const int hu = r >> 2, g = r & 3;
    const int srow = l * NG + g * NH + hu;
    bias[idx] = b_ih[srow] + b_hh[srow];
  }
}

// ---------------- prep: x0, projection weights, flag reset ----------------
__global__ void k_prep_misc(const float* __restrict__ embed, const int* __restrict__ start_idx,
                            const float* __restrict__ w1, const float* __restrict__ b1,
                            const float* __restrict__ w2, const float* __restrict__ b2,
                            _Float16* __restrict__ x0, _Float16* __restrict__ pw1, float* __restrict__ pb1,
                            _Float16* __restrict__ pw2, float* __restrict__ pb2, int* __restrict__ flags) {
  const int stride = gridDim.x * blockDim.x;
  const int tid0 = blockIdx.x * blockDim.x + threadIdx.x;
  for (int i = tid0; i < 256 * 16; i += stride) flags[i] = 0;
  const int st = start_idx[0];
  for (int i = tid0; i < NB * NH; i += stride)
    x0[i] = (_Float16)embed[(size_t)st * NH + (i & (NH - 1))];
  for (int i = tid0; i < 2 * NH * NH; i += stride)
    pw1[i] = (_Float16)w1[i];
  for (int i = tid0; i < NVP * NK; i += stride) {
    const int r = i >> 10;
    pw2[i] = (_Float16)((r < NV) ? w2[i] : 0.f);
  }
  for (int i = tid0; i < 2 * NH; i += stride) pb1[i] = b1[i];
  for (int i = tid0; i < NVP; i += stride) pb2[i] = (i < NV) ? b2[i] : 0.f;
}

// ---------------- visual GEMV: out[b][j] = dot(x[b,:], w[j,:]) + bias[j] (f32) ----------------
__global__ void k_gemv512(const float* __restrict__ x, const float* __restrict__ w,
                          const float* __restrict__ bias, float* __restrict__ out) {
  const int b = blockIdx.x;
  __shared__ float xs[NH];
  for (int i = threadIdx.x; i < NH; i += 256) xs[i] = x[(size_t)b * NH + i];
  __syncthreads();
  const int wave = threadIdx.x >> 6, lane = threadIdx.x & 63;
  for (int j = wave; j < NH; j += 4) {
    const float* wr = w + (size_t)j * NH;
    float s = 0.f;
#pragma unroll
    for (int i = 0; i < 8; ++i) s += wr[lane + i * 64] * xs[lane + i * 64];
#pragma unroll
    for (int o = 32; o > 0; o >>= 1) s += __shfl_down(s, o);
    if (lane == 0) out[(size_t)b * NH + j] = s + bias[j];
  }
}

// second visual GEMV + broadcast h0 into all layers (parity 0) + zero c
__global__ void k_gemv2_init(const float* __restrict__ feat1, const float* __restrict__ w,
                             const float* __restrict__ bias, _Float16* __restrict__ hbuf,
                             float* __restrict__ cbuf) {
  const int b = blockIdx.x;
  __shared__ float xs[NH];
  for (int i = threadIdx.x; i < NH; i += 256) xs[i] = feat1[(size_t)b * NH + i];
  __syncthreads();
  const int wave = threadIdx.x >> 6, lane = threadIdx.x & 63;
  for (int j = wave; j < NH; j += 4) {
    const float* wr = w + (size_t)j * NH;
    float s = 0.f;
#pragma unroll
    for (int i = 0; i < 8; ++i) s += wr[lane + i * 64] * xs[lane + i * 64];
#pragma unroll
    for (int o = 32; o > 0; o >>= 1) s += __shfl_down(s, o);
    if (lane == 0) {
      const float hv = s + bias[j];
      const _Float16 h16 = (_Float16)hv;
#pragma unroll
      for (int l = 0; l < NL; ++l) {
        hbuf[((size_t)(l * 2 + 0) * NB + b) * NH + j] = h16;  // parity 0
        cbuf[((size_t)l * NB + b) * NH + j] = 0.f;
      }
    }
  }
}

// ---------------- persistent LSTM recurrence ----------------
// 256 blocks. bm = bid>>5 (batch-slice group of 32 blocks), bn = (bid&7)*4 + ((bid>>3)&3)
// so that XCD (= bid%8, round-robin heuristic) hosts only 4 gate-slices -> W stays L2-resident.
// Each wave owns 16 gate rows x full 32-batch (W read once per block). Group-local flag barrier.
__global__ __launch_bounds__(256) void k_lstm(const _Float16* __restrict__ W, const float* __restrict__ bias,
                                              _Float16* __restrict__ hbuf, float* __restrict__ cbuf,
                                              const _Float16* __restrict__ x0, _Float16* __restrict__ outs,
                                              const int* __restrict__ rowmap, const int* __restrict__ colmap,
                                              int* __restrict__ flags) {
  const int tid = threadIdx.x;
  const int lane = tid & 63;
  const int wave = tid >> 6;
  const int bid = blockIdx.x;
  const int j = bid & 31;
  const int bm = bid >> 5;                   // batch slice (32 rows), group id
  const int bn = (j & 7) * 4 + (j >> 3);     // gate slice (64 permuted rows = 16 hidden units)
  const int gbase = bm * 32;
  const int lr = lane & 15;
  const int lh = lane >> 4;
  const int aoff0 = (bm * 32 + lr) * NH + lh * 8;       // batch rows 0-15
  const int aoff1 = (bm * 32 + 16 + lr) * NH + lh * 8;  // batch rows 16-31
  const int nb0 = bn * 64 + wave * 16;                  // this wave's 16 gate rows
  const size_t boff = (size_t)(nb0 + lr) * NK + lh * 8;
  __shared__ float gl[32][68];
  int phase = 0;

  int rm[4], cm[4];
#pragma unroll
  for (int r = 0; r < 4; ++r) {
    rm[r] = rowmap[lane * 4 + r];
    cm[r] = colmap[lane * 4 + r];
  }
  float bsv[2][NL][4];
#pragma unroll
  for (int rep = 0; rep < 2; ++rep) {
    const int item = tid + rep * 256;
    const int hu = item & 15;
    const int hg = bn * 16 + hu;
#pragma unroll
    for (int l = 0; l < NL; ++l)
#pragma unroll
      for (int g = 0; g < 4; ++g) bsv[rep][l][g] = bias[l * NG + hg * 4 + g];
  }

#pragma unroll 1
  for (int t = 0; t < NT; ++t) {
    const int p = t & 1;
#pragma unroll 1
    for (int l = 0; l < NL; ++l) {
      const _Float16* xin = (l == 0) ? ((t == 0) ? x0 : hbuf + (size_t)(2 * 2 + p) * NB * NH)
                                     : hbuf + (size_t)((l - 1) * 2 + (p ^ 1)) * NB * NH;
      const _Float16* hprev = hbuf + (size_t)(l * 2 + p) * NB * NH;
      const _Float16* Wl = W + (size_t)l * NG * NK;
      f32x4 acc0 = {0.f, 0.f, 0.f, 0.f};
      f32x4 acc1 = {0.f, 0.f, 0.f, 0.f};
#pragma unroll 4
      for (int kk = 0; kk < 32; ++kk) {
        const _Float16* Ap = (kk < 16) ? xin : hprev;
        const int ko = (kk & 15) * 32;
        f16x8 av0 = *(const f16x8*)(Ap + aoff0 + ko);
        f16x8 av1 = *(const f16x8*)(Ap + aoff1 + ko);
        f16x8 bv = *(const f16x8*)(Wl + boff + (size_t)kk * 32);
        acc0 = __builtin_amdgcn_mfma_f32_16x16x32_f16(av0, bv, acc0, 0, 0, 0);
        acc1 = __builtin_amdgcn_mfma_f32_16x16x32_f16(av1, bv, acc1, 0, 0, 0);
      }
      // D(lane,r) = (A-row rm[r], B-row cm[r]); local gate col = wave*16 + cm[r]
#pragma unroll
      for (int r = 0; r < 4; ++r) {
        gl[rm[r]][wave * 16 + cm[r]] = acc0[r];
        gl[16 + rm[r]][wave * 16 + cm[r]] = acc1[r];
      }
      __syncthreads();
      _Float16* hnew = hbuf + (size_t)(l * 2 + (p ^ 1)) * NB * NH;
#pragma unroll
      for (int rep = 0; rep < 2; ++rep) {
        const int item = tid + rep * 256;
        const int bl_ = item >> 4;
        const int hu = item & 15;
        const float gi = gl[bl_][hu * 4 + 0] + bsv[rep][l][0];
        const float gf = gl[bl_][hu * 4 + 1] + bsv[rep][l][1];
        const float gg = gl[bl_][hu * 4 + 2] + bsv[rep][l][2];
        const float go = gl[bl_][hu * 4 + 3] + bsv[rep][l][3];
        const int bg = bm * 32 + bl_;
        const int hg = bn * 16 + hu;
        float* cp = cbuf + ((size_t)l * NB + bg) * NH + hg;
        const float cold = *cp;
        const float cn = sigf(gf) * cold + sigf(gi) * tanhf_(gg);
        const float hn = sigf(go) * tanhf_(cn);
        *cp = cn;
        const _Float16 hv = (_Float16)hn;
        hnew[(size_t)bg * NH + hg] = hv;
        if (l == 2) outs[((size_t)t * NB + bg) * NH + hg] = hv;
      }
      ++phase;
      group_bar(flags, gbase, j, tid, phase);
    }
  }
}

// ---------------- projection head: gelu(res@W1^T+b1)@W2^T+b2 -> out[b][v][t] (f32) ----------------
__global__ __launch_bounds__(256) void k_proj(const _Float16* __restrict__ outs, const _Float16* __restrict__ pw1,
                                              const float* __restrict__ pb1, const _Float16* __restrict__ pw2,
                                              const float* __restrict__ pb2,
                                              const int* __restrict__ rowmap, const int* __restrict__ colmap,
                                              float* __restrict__ out) {
  const int tid = threadIdx.x;
  const int lane = tid & 63;
  const int wave = tid >> 6;
  const int lr = lane & 15;
  const int lh = lane >> 4;
  const int mbase = blockIdx.x * 16;
  __shared__ _Float16 hm[16][NK + 8];
  int rm[4], cm[4];
#pragma unroll
  for (int r = 0; r < 4; ++r) {
    rm[r] = rowmap[lane * 4 + r];
    cm[r] = colmap[lane * 4 + r];
  }
  const int mrow = mbase + lr;
  const _Float16* ap = outs + ((size_t)(mrow % NT) * NB + (mrow / NT)) * NH + lh * 8;
  // phase 1: hmid[16][1024]
  for (int nf = 0; nf < 16; ++nf) {
    const int n0 = wave * 256 + nf * 16;
    f32x4 acc = {0.f, 0.f, 0.f, 0.f};
    const _Float16* bp = pw1 + (size_t)(n0 + lr) * NH + lh * 8;
#pragma unroll 4
    for (int kk = 0; kk < 16; ++kk) {
      f16x8 a = *(const f16x8*)(ap + kk * 32);
      f16x8 b = *(const f16x8*)(bp + kk * 32);
      acc = __builtin_amdgcn_mfma_f32_16x16x32_f16(a, b, acc, 0, 0, 0);
    }
#pragma unroll
    for (int r = 0; r < 4; ++r) {
      const float v = acc[r] + pb1[n0 + cm[r]];
      const float gv = 0.5f * v * (1.f + erff(v * 0.70710678118654752f));
      hm[rm[r]][n0 + cm[r]] = (_Float16)gv;
    }
  }
  __syncthreads();
  // phase 2: logits[16][112], K=1024 from LDS
  for (int nf = wave; nf < 7; nf += 4) {
    const int n0 = nf * 16;
    f32x4 acc = {0.f, 0.f, 0.f, 0.f};
    const _Float16* bp = pw2 + (size_t)(n0 + lr) * NK + lh * 8;
#pragma unroll 4
    for (int kk = 0; kk < 32; ++kk) {
      f16x8 a = *(const f16x8*)(&hm[lr][kk * 32 + lh * 8]);
      f16x8 b = *(const f16x8*)(bp + kk * 32);
      acc = __builtin_amdgcn_mfma_f32_16x16x32_f16(a, b, acc, 0, 0, 0);
    }
#pragma unroll
    for (int r = 0; r < 4; ++r) {
      const int v = n0 + cm[r];
      if (v < NV) {
        const int m = mbase + rm[r];
        out[((size_t)(m / NT) * NV + v) * NT + (m % NT)] = acc[r] + pb2[v];
      }
    }
  }
}

extern "C" void kernel_launch(void* const* d_in, const int* in_sizes, int n_in,
                              void* d_out, int out_size, void* d_ws, size_t ws_size,
                              hipStream_t stream) {
  const float* feat = (const float*)d_in[0];
  const float* visual_w = (const float*)d_in[1];
  const float* visual_b = (const float*)d_in[2];
  const float* embed = (const float*)d_in[3];
  const float* w_ih = (const float*)d_in[4];
  const float* w_hh = (const float*)d_in[5];
  const float* b_ih = (const float*)d_in[6];
  const float* b_hh = (const float*)d_in[7];
  const float* proj_w1 = (const float*)d_in[8];
  const float* proj_b1 = (const float*)d_in[9];
  const float* proj_w2 = (const float*)d_in[10];
  const float* proj_b2 = (const float*)d_in[11];
  const int* start_idx = (const int*)d_in[12];
  float* out = (float*)d_out;  // reference output dtype is float32

  char* ws = (char*)d_ws;
  size_t off = 0;
  auto alloc = [&](size_t bytes) -> void* {
    void* p = ws + off;
    off += (bytes + 255) & ~(size_t)255;
    return p;
  };
  _Float16* W = (_Float16*)alloc((size_t)NL * NG * NK * 2);
  float* bias = (float*)alloc((size_t)NL * NG * 4);
  _Float16* hbuf = (_Float16*)alloc((size_t)6 * NB * NH * 2);  // [l][parity][B][H]
  float* cbuf = (float*)alloc((size_t)NL * NB * NH * 4);
  _Float16* x0 = (_Float16*)alloc((size_t)NB * NH * 2);
  _Float16* outsb = (_Float16*)alloc((size_t)NT * NB * NH * 2);
  float* feat1 = (float*)alloc((size_t)NB * NH * 4);
  _Float16* pw1 = (_Float16*)alloc((size_t)2 * NH * NH * 2);
  _Float16* pw2 = (_Float16*)alloc((size_t)NVP * NK * 2);
  float* pb1 = (float*)alloc((size_t)2 * NH * 4);
  float* pb2 = (float*)alloc((size_t)NVP * 4);
  int* flags = (int*)alloc(256 * 16 * 4);
  int* rowmap = (int*)alloc(256 * 4);
  int* colmap = (int*)alloc(256 * 4);
  if (off > ws_size) return;  // insufficient workspace — fail visibly

  k_probe<<<dim3(1), dim3(64), 0, stream>>>(rowmap, colmap);
  k_prep_w<<<dim3(2048), dim3(256), 0, stream>>>(w_ih, w_hh, b_ih, b_hh, W, bias);
  k_prep_misc<<<dim3(1024), dim3(256), 0, stream>>>(embed, start_idx, proj_w1, proj_b1, proj_w2, proj_b2,
                                                    x0, pw1, pb1, pw2, pb2, flags);
  k_gemv512<<<dim3(NB), dim3(256), 0, stream>>>(feat, visual_w, visual_b, feat1);
  k_gemv2_init<<<dim3(NB), dim3(256), 0, stream>>>(feat1, visual_w, visual_b, hbuf, cbuf);
  k_lstm<<<dim3(256), dim3(256), 0, stream>>>(W, bias, hbuf, cbuf, x0, outsb, rowmap, colmap, flags);
  k_proj<<<dim3(3200), dim3(256), 0, stream>>>(outsb, pw1, pb1, pw2, pb2, rowmap, colmap, out);
}

// Round 8
// 7525.177 us; speedup vs baseline: 3.8133x; 3.4828x over previous
//
#include <hip/hip_runtime.h>
#include <hip/hip_bf16.h>
#include <hip/hip_fp16.h>

// Problem constants
#define NB 256   // batch
#define NH 512   // hidden
#define NL 3     // lstm layers
#define NT 200   // time steps
#define NV 100   // vocab
#define NVP 112  // vocab padded to 7*16
#define NG 2048  // 4*NH gates
#define NK 1024  // 2*NH (x|h concat K)

using f16x8 = __attribute__((ext_vector_type(8))) _Float16;
using f32x4 = __attribute__((ext_vector_type(4))) float;
using u32x4 = __attribute__((ext_vector_type(4))) unsigned int;

__device__ __forceinline__ float sigf(float x) { return 1.f / (1.f + __expf(-x)); }
__device__ __forceinline__ float tanhf_(float x) { return 2.f / (1.f + __expf(-2.f * x)) - 1.f; }

// ---------------- MFMA layout probe ----------------
__global__ void k_probe(int* __restrict__ rowmap, int* __restrict__ colmap) {
  const int lane = threadIdx.x & 63;
  f16x8 a, b;
  const _Float16 idv = (_Float16)(float)(lane & 15);
  const _Float16 inv = (_Float16)(1.f / 32.f);
#pragma unroll
  for (int j = 0; j < 8; ++j) { a[j] = idv; b[j] = inv; }
  f32x4 d = {0.f, 0.f, 0.f, 0.f};
  d = __builtin_amdgcn_mfma_f32_16x16x32_f16(a, b, d, 0, 0, 0);
#pragma unroll
  for (int r = 0; r < 4; ++r) rowmap[lane * 4 + r] = (int)(d[r] + 0.5f);
#pragma unroll
  for (int j = 0; j < 8; ++j) { a[j] = inv; b[j] = idv; }
  f32x4 e = {0.f, 0.f, 0.f, 0.f};
  e = __builtin_amdgcn_mfma_f32_16x16x32_f16(a, b, e, 0, 0, 0);
#pragma unroll
  for (int r = 0; r < 4; ++r) colmap[lane * 4 + r] = (int)(e[r] + 0.5f);
}

// ---------------- prep: permute+convert recurrent weights to fp16 ----------------
__global__ void k_prep_w(const float* __restrict__ w_ih, const float* __restrict__ w_hh,
                         const float* __restrict__ b_ih, const float* __restrict__ b_hh,
                         _Float16* __restrict__ W, float* __restrict__ bias) {
  const int stride = gridDim.x * blockDim.x;
  const int tid0 = blockIdx.x * blockDim.x + threadIdx.x;
  for (int idx = tid0; idx < NL * NG * NK; idx += stride) {
    const int k = idx & (NK - 1);
    const int r = (idx >> 10) & (NG - 1);
    const int l = idx >> 21;
    const int hu = r >> 2, g = r & 3;
    const int srow = l * NG + g * NH + hu;
    const float v = (k < NH) ? w_ih[(size_t)srow * NH + k]
                             : w_hh[(size_t)srow * NH + (k - NH)];
    W[idx] = (_Float16)v;
  }
  for (int idx = tid0; idx < NL * NG; idx += stride) {
    const int r = idx & (NG - 1);
    const int l = idx >> 11;
    const int hu = r >> 2, g = r & 3;
    const int srow = l * NG + g * NH + hu;
    bias[idx] = b_ih[srow] + b_hh[srow];
  }
}

// ---------------- prep: x0, projection weights, flag reset ----------------
__global__ void k_prep_misc(const float* __restrict__ embed, const int* __restrict__ start_idx,
                            const float* __restrict__ w1, const float* __restrict__ b1,
                            const float* __restrict__ w2, const float* __restrict__ b2,
                            _Float16* __restrict__ x0, _Float16* __restrict__ pw1, float* __restrict__ pb1,
                            _Float16* __restrict__ pw2, float* __restrict__ pb2, int* __restrict__ flags) {
  const int stride = gridDim.x * blockDim.x;
  const int tid0 = blockIdx.x * blockDim.x + threadIdx.x;
  for (int i = tid0; i < 256 * 16; i += stride) flags[i] = 0;
  const int st = start_idx[0];
  for (int i = tid0; i < NB * NH; i += stride)
    x0[i] = (_Float16)embed[(size_t)st * NH + (i & (NH - 1))];
  for (int i = tid0; i < 2 * NH * NH; i += stride)
    pw1[i] = (_Float16)w1[i];
  for (int i = tid0; i < NVP * NK; i += stride) {
    const int r = i >> 10;
    pw2[i] = (_Float16)((r < NV) ? w2[i] : 0.f);
  }
  for (int i = tid0; i < 2 * NH; i += stride) pb1[i] = b1[i];
  for (int i = tid0; i < NVP; i += stride) pb2[i] = (i < NV) ? b2[i] : 0.f;
}

// ---------------- visual GEMV ----------------
__global__ void k_gemv512(const float* __restrict__ x, const float* __restrict__ w,
                          const float* __restrict__ bias, float* __restrict__ out) {
  const int b = blockIdx.x;
  __shared__ float xs[NH];
  for (int i = threadIdx.x; i < NH; i += 256) xs[i] = x[(size_t)b * NH + i];
  __syncthreads();
  const int wave = threadIdx.x >> 6, lane = threadIdx.x & 63;
  for (int j = wave; j < NH; j += 4) {
    const float* wr = w + (size_t)j * NH;
    float s = 0.f;
#pragma unroll
    for (int i = 0; i < 8; ++i) s += wr[lane + i * 64] * xs[lane + i * 64];
#pragma unroll
    for (int o = 32; o > 0; o >>= 1) s += __shfl_down(s, o);
    if (lane == 0) out[(size_t)b * NH + j] = s + bias[j];
  }
}

// second visual GEMV + broadcast h0 into all layers (parity 0)
__global__ void k_gemv2_init(const float* __restrict__ feat1, const float* __restrict__ w,
                             const float* __restrict__ bias, _Float16* __restrict__ hbuf) {
  const int b = blockIdx.x;
  __shared__ float xs[NH];
  for (int i = threadIdx.x; i < NH; i += 256) xs[i] = feat1[(size_t)b * NH + i];
  __syncthreads();
  const int wave = threadIdx.x >> 6, lane = threadIdx.x & 63;
  for (int j = wave; j < NH; j += 4) {
    const float* wr = w + (size_t)j * NH;
    float s = 0.f;
#pragma unroll
    for (int i = 0; i < 8; ++i) s += wr[lane + i * 64] * xs[lane + i * 64];
#pragma unroll
    for (int o = 32; o > 0; o >>= 1) s += __shfl_down(s, o);
    if (lane == 0) {
      const float hv = s + bias[j];
      const _Float16 h16 = (_Float16)hv;
#pragma unroll
      for (int l = 0; l < NL; ++l)
        hbuf[((size_t)(l * 2 + 0) * NB + b) * NH + j] = h16;  // parity 0
    }
  }
}

// ---------------- persistent LSTM recurrence (fence-free, coherent h exchange) ----------------
// 256 blocks x 512 threads (8 waves). bm = bid>>5 (group of 32 blocks = one 32-row batch slice),
// bn = (j&7)*4+(j>>3) so each XCD (bid%8 heuristic) hosts 4 gate-slices -> W L2-resident.
// NO fences/acquires anywhere: h + flags use volatile (sc0 sc1, coherent at L3); W/bias/outs
// normal cached (never invalidated); c lives in 3 VGPRs per thread. A (xin|hprev) is staged
// once per block into LDS via volatile loads, MFMA A-fragments read from LDS.
__global__ __launch_bounds__(512) void k_lstm(const _Float16* __restrict__ W, const float* __restrict__ bias,
                                              _Float16* hbuf, const _Float16* __restrict__ x0,
                                              _Float16* __restrict__ outs,
                                              const int* __restrict__ rowmap, const int* __restrict__ colmap,
                                              int* flags) {
  const int tid = threadIdx.x;
  const int lane = tid & 63;
  const int wave = tid >> 6;               // 0..7
  const int bid = blockIdx.x;
  const int j = bid & 31;
  const int bm = bid >> 5;                 // batch-slice group
  const int bn = (j & 7) * 4 + (j >> 3);   // gate slice (64 permuted rows = 16 hidden units)
  const int gbase = bm * 32;
  const int wm = wave & 1;                 // batch 16-half
  const int wn = wave >> 1;                // gate 16-quarter
  const int lr = lane & 15;
  const int lh = lane >> 4;                // 0..3
  const size_t boff = (size_t)(bn * 64 + wn * 16 + lr) * NK + lh * 8;
  __shared__ _Float16 Als[32][1032];       // staged [xin|hprev], 16B-aligned rows, 2-way-bank-free-ish
  __shared__ float gl[32][68];
  int phase = 0;

  int rm[4], cm[4];
#pragma unroll
  for (int r = 0; r < 4; ++r) {
    rm[r] = rowmap[lane * 4 + r];
    cm[r] = colmap[lane * 4 + r];
  }
  // cell-update ownership: thread -> (batch row bl_, hidden unit hu); c in registers
  const int bl_ = tid >> 4;                // 0..31
  const int hu = tid & 15;
  float creg[NL] = {0.f, 0.f, 0.f};
  float bsv[NL][4];
#pragma unroll
  for (int l = 0; l < NL; ++l)
#pragma unroll
    for (int g = 0; g < 4; ++g) bsv[l][g] = bias[l * NG + (bn * 16 + hu) * 4 + g];

#pragma unroll 1
  for (int t = 0; t < NT; ++t) {
    const int p = t & 1;
#pragma unroll 1
    for (int l = 0; l < NL; ++l) {
      const _Float16* xin = (l == 0) ? ((t == 0) ? x0 : hbuf + (size_t)(2 * 2 + p) * NB * NH)
                                     : hbuf + (size_t)((l - 1) * 2 + (p ^ 1)) * NB * NH;
      const _Float16* hprev = hbuf + (size_t)(l * 2 + p) * NB * NH;
      // stage A = [xin rows | hprev rows] for this group's 32 batch rows (coherent loads)
      {
        const _Float16* xr = xin + (size_t)(bm * 32) * NH;
        const _Float16* hr = hprev + (size_t)(bm * 32) * NH;
#pragma unroll
        for (int c = 0; c < 8; ++c) {
          const int i = tid + c * 512;     // 0..4095 16B chunks
          const int r = i >> 7;            // row 0..31
          const int cc = i & 127;          // chunk in row (128 x 16B = 2KB = 1024 fp16)
          const _Float16* src = (cc < 64) ? (xr + (size_t)r * NH + cc * 8)
                                          : (hr + (size_t)r * NH + (cc - 64) * 8);
          u32x4 v = *(const volatile u32x4*)src;
          *(u32x4*)&Als[r][cc * 8] = v;
        }
      }
      __syncthreads();
      // gates GEMM: each wave one 16x16 tile, K = 1024 from LDS(A) x L2-warm global(W)
      const _Float16* Wl = W + (size_t)l * NG * NK;
      f32x4 acc = {0.f, 0.f, 0.f, 0.f};
      const int arow = wm * 16 + lr;
#pragma unroll 4
      for (int kk = 0; kk < 32; ++kk) {
        f16x8 av = *(const f16x8*)&Als[arow][kk * 32 + lh * 8];
        f16x8 bv = *(const f16x8*)(Wl + boff + (size_t)kk * 32);
        acc = __builtin_amdgcn_mfma_f32_16x16x32_f16(av, bv, acc, 0, 0, 0);
      }
#pragma unroll
      for (int r = 0; r < 4; ++r)
        gl[wm * 16 + rm[r]][wn * 16 + cm[r]] = acc[r];
      __syncthreads();
      // cell update (c in registers), coherent h store
      {
        const float gi = gl[bl_][hu * 4 + 0] + bsv[l][0];
        const float gf = gl[bl_][hu * 4 + 1] + bsv[l][1];
        const float gg = gl[bl_][hu * 4 + 2] + bsv[l][2];
        const float go = gl[bl_][hu * 4 + 3] + bsv[l][3];
        const float cn = sigf(gf) * creg[l] + sigf(gi) * tanhf_(gg);
        const float hn = sigf(go) * tanhf_(cn);
        creg[l] = cn;
        const int bg = bm * 32 + bl_;
        const int hg = bn * 16 + hu;
        volatile _Float16* hnew = hbuf + (size_t)(l * 2 + (p ^ 1)) * NB * NH;
        hnew[(size_t)bg * NH + hg] = (_Float16)hn;
        if (l == 2) outs[((size_t)t * NB + bg) * NH + hg] = (_Float16)hn;
      }
      // fence-free group barrier: syncthreads drains all waves' vmem; flag is write-through
      asm volatile("s_waitcnt vmcnt(0)" ::: "memory");
      __syncthreads();
      ++phase;
      if (tid == 0) *(volatile int*)&flags[(gbase + j) * 16] = phase;
      if (tid < 32) {
        const volatile int* fp = (const volatile int*)&flags[(gbase + tid) * 16];
        while (*fp < phase) __builtin_amdgcn_s_sleep(1);
      }
      __syncthreads();
    }
  }
}

// ---------------- projection head: gelu(res@W1^T+b1)@W2^T+b2 -> out[b][v][t] (f32) ----------------
__global__ __launch_bounds__(256) void k_proj(const _Float16* __restrict__ outs, const _Float16* __restrict__ pw1,
                                              const float* __restrict__ pb1, const _Float16* __restrict__ pw2,
                                              const float* __restrict__ pb2,
                                              const int* __restrict__ rowmap, const int* __restrict__ colmap,
                                              float* __restrict__ out) {
  const int tid = threadIdx.x;
  const int lane = tid & 63;
  const int wave = tid >> 6;
  const int lr = lane & 15;
  const int lh = lane >> 4;
  const int mbase = blockIdx.x * 16;
  __shared__ _Float16 hm[16][NK + 8];
  int rm[4], cm[4];
#pragma unroll
  for (int r = 0; r < 4; ++r) {
    rm[r] = rowmap[lane * 4 + r];
    cm[r] = colmap[lane * 4 + r];
  }
  const int mrow = mbase + lr;
  const _Float16* ap = outs + ((size_t)(mrow % NT) * NB + (mrow / NT)) * NH + lh * 8;
  for (int nf = 0; nf < 16; ++nf) {
    const int n0 = wave * 256 + nf * 16;
    f32x4 acc = {0.f, 0.f, 0.f, 0.f};
    const _Float16* bp = pw1 + (size_t)(n0 + lr) * NH + lh * 8;
#pragma unroll 4
    for (int kk = 0; kk < 16; ++kk) {
      f16x8 a = *(const f16x8*)(ap + kk * 32);
      f16x8 b = *(const f16x8*)(bp + kk * 32);
      acc = __builtin_amdgcn_mfma_f32_16x16x32_f16(a, b, acc, 0, 0, 0);
    }
#pragma unroll
    for (int r = 0; r < 4; ++r) {
      const float v = acc[r] + pb1[n0 + cm[r]];
      const float gv = 0.5f * v * (1.f + erff(v * 0.70710678118654752f));
      hm[rm[r]][n0 + cm[r]] = (_Float16)gv;
    }
  }
  __syncthreads();
  for (int nf = wave; nf < 7; nf += 4) {
    const int n0 = nf * 16;
    f32x4 acc = {0.f, 0.f, 0.f, 0.f};
    const _Float16* bp = pw2 + (size_t)(n0 + lr) * NK + lh * 8;
#pragma unroll 4
    for (int kk = 0; kk < 32; ++kk) {
      f16x8 a = *(const f16x8*)(&hm[lr][kk * 32 + lh * 8]);
      f16x8 b = *(const f16x8*)(bp + kk * 32);
      acc = __builtin_amdgcn_mfma_f32_16x16x32_f16(a, b, acc, 0, 0, 0);
    }
#pragma unroll
    for (int r = 0; r < 4; ++r) {
      const int v = n0 + cm[r];
      if (v < NV) {
        const int m = mbase + rm[r];
        out[((size_t)(m / NT) * NV + v) * NT + (m % NT)] = acc[r] + pb2[v];
      }
    }
  }
}

extern "C" void kernel_launch(void* const* d_in, const int* in_sizes, int n_in,
                              void* d_out, int out_size, void* d_ws, size_t ws_size,
                              hipStream_t stream) {
  const float* feat = (const float*)d_in[0];
  const float* visual_w = (const float*)d_in[1];
  const float* visual_b = (const float*)d_in[2];
  const float* embed = (const float*)d_in[3];
  const float* w_ih = (const float*)d_in[4];
  const float* w_hh = (const float*)d_in[5];
  const float* b_ih = (const float*)d_in[6];
  const float* b_hh = (const float*)d_in[7];
  const float* proj_w1 = (const float*)d_in[8];
  const float* proj_b1 = (const float*)d_in[9];
  const float* proj_w2 = (const float*)d_in[10];
  const float* proj_b2 = (const float*)d_in[11];
  const int* start_idx = (const int*)d_in[12];
  float* out = (float*)d_out;  // reference output dtype is float32

  char* ws = (char*)d_ws;
  size_t off = 0;
  auto alloc = [&](size_t bytes) -> void* {
    void* p = ws + off;
    off += (bytes + 255) & ~(size_t)255;
    return p;
  };
  _Float16* W = (_Float16*)alloc((size_t)NL * NG * NK * 2);
  float* bias = (float*)alloc((size_t)NL * NG * 4);
  _Float16* hbuf = (_Float16*)alloc((size_t)6 * NB * NH * 2);  // [l][parity][B][H]
  _Float16* x0 = (_Float16*)alloc((size_t)NB * NH * 2);
  _Float16* outsb = (_Float16*)alloc((size_t)NT * NB * NH * 2);
  float* feat1 = (float*)alloc((size_t)NB * NH * 4);
  _Float16* pw1 = (_Float16*)alloc((size_t)2 * NH * NH * 2);
  _Float16* pw2 = (_Float16*)alloc((size_t)NVP * NK * 2);
  float* pb1 = (float*)alloc((size_t)2 * NH * 4);
  float* pb2 = (float*)alloc((size_t)NVP * 4);
  int* flags = (int*)alloc(256 * 16 * 4);
  int* rowmap = (int*)alloc(256 * 4);
  int* colmap = (int*)alloc(256 * 4);
  if (off > ws_size) return;  // insufficient workspace — fail visibly

  k_probe<<<dim3(1), dim3(64), 0, stream>>>(rowmap, colmap);
  k_prep_w<<<dim3(2048), dim3(256), 0, stream>>>(w_ih, w_hh, b_ih, b_hh, W, bias);
  k_prep_misc<<<dim3(1024), dim3(256), 0, stream>>>(embed, start_idx, proj_w1, proj_b1, proj_w2, proj_b2,
                                                    x0, pw1, pb1, pw2, pb2, flags);
  k_gemv512<<<dim3(NB), dim3(256), 0, stream>>>(feat, visual_w, visual_b, feat1);
  k_gemv2_init<<<dim3(NB), dim3(256), 0, stream>>>(feat1, visual_w, visual_b, hbuf);
  k_lstm<<<dim3(256), dim3(512), 0, stream>>>(W, bias, hbuf, x0, outsb, rowmap, colmap, flags);
  k_proj<<<dim3(3200), dim3(256), 0, stream>>>(outsb, pw1, pb1, pw2, pb2, rowmap, colmap, out);
}

// Round 9
// 4887.131 us; speedup vs baseline: 5.8717x; 1.5398x over previous
//
#include <hip/hip_runtime.h>
#include <hip/hip_bf16.h>
#include <hip/hip_fp16.h>

// Problem constants
#define NB 256   // batch
#define NH 512   // hidden
#define NL 3     // lstm layers
#define NT 200   // time steps
#define NV 100   // vocab
#define NVP 112  // vocab padded to 7*16
#define NG 2048  // 4*NH gate rows per layer (permuted r = hu*4+g)
#define NK 1024  // 2*NH (proj2 K)
#define NS (NT * NL)  // 600 chain stages; cell s=(t,l), s=3t+l; input(s) = output(s-1)

using f16x8 = __attribute__((ext_vector_type(8))) _Float16;
using f32x4 = __attribute__((ext_vector_type(4))) float;
using u32x4 = __attribute__((ext_vector_type(4))) unsigned int;

__device__ __forceinline__ float sigf(float x) { return 1.f / (1.f + __expf(-x)); }
__device__ __forceinline__ float tanhf_(float x) { return 2.f / (1.f + __expf(-2.f * x)) - 1.f; }

// ---------------- MFMA layout probe ----------------
__global__ void k_probe(int* __restrict__ rowmap, int* __restrict__ colmap) {
  const int lane = threadIdx.x & 63;
  f16x8 a, b;
  const _Float16 idv = (_Float16)(float)(lane & 15);
  const _Float16 inv = (_Float16)(1.f / 32.f);
#pragma unroll
  for (int j = 0; j < 8; ++j) { a[j] = idv; b[j] = inv; }
  f32x4 d = {0.f, 0.f, 0.f, 0.f};
  d = __builtin_amdgcn_mfma_f32_16x16x32_f16(a, b, d, 0, 0, 0);
#pragma unroll
  for (int r = 0; r < 4; ++r) rowmap[lane * 4 + r] = (int)(d[r] + 0.5f);
#pragma unroll
  for (int j = 0; j < 8; ++j) { a[j] = inv; b[j] = idv; }
  f32x4 e = {0.f, 0.f, 0.f, 0.f};
  e = __builtin_amdgcn_mfma_f32_16x16x32_f16(a, b, e, 0, 0, 0);
#pragma unroll
  for (int r = 0; r < 4; ++r) colmap[lane * 4 + r] = (int)(e[r] + 0.5f);
}

// ---------------- prep: split + permute recurrent weights to fp16 ----------------
// Wih/Whh[l][r][k], r = hu*4+g (permuted), k 0..511. bias[l][r] = b_ih + b_hh.
__global__ void k_prep_w(const float* __restrict__ w_ih, const float* __restrict__ w_hh,
                         const float* __restrict__ b_ih, const float* __restrict__ b_hh,
                         _Float16* __restrict__ Wih, _Float16* __restrict__ Whh,
                         float* __restrict__ bias) {
  const int stride = gridDim.x * blockDim.x;
  const int tid0 = blockIdx.x * blockDim.x + threadIdx.x;
  for (int idx = tid0; idx < NL * NG * NH; idx += stride) {
    const int k = idx & (NH - 1);
    const int r = (idx >> 9) & (NG - 1);
    const int l = idx >> 20;
    const int hu = r >> 2, g = r & 3;
    const size_t soff = ((size_t)(l * NG + g * NH + hu)) * NH + k;
    Wih[idx] = (_Float16)w_ih[soff];
    Whh[idx] = (_Float16)w_hh[soff];
  }
  for (int idx = tid0; idx < NL * NG; idx += stride) {
    const int r = idx & (NG - 1);
    const int l = idx >> 11;
    const int hu = r >> 2, g = r & 3;
    const int srow = l * NG + g * NH + hu;
    bias[idx] = b_ih[srow] + b_hh[srow];
  }
}

// ---------------- prep: x0, projection weights, flag reset ----------------
__global__ void k_prep_misc(const float* __restrict__ embed, const int* __restrict__ start_idx,
                            const float* __restrict__ w1, const float* __restrict__ b1,
                            const float* __restrict__ w2, const float* __restrict__ b2,
                            _Float16* __restrict__ x0, _Float16* __restrict__ pw1, float* __restrict__ pb1,
                            _Float16* __restrict__ pw2, float* __restrict__ pb2, int* __restrict__ flags) {
  const int stride = gridDim.x * blockDim.x;
  const int tid0 = blockIdx.x * blockDim.x + threadIdx.x;
  for (int i = tid0; i < 256 * 16; i += stride) flags[i] = 0;
  const int st = start_idx[0];
  for (int i = tid0; i < NB * NH; i += stride)
    x0[i] = (_Float16)embed[(size_t)st * NH + (i & (NH - 1))];
  for (int i = tid0; i < 2 * NH * NH; i += stride)
    pw1[i] = (_Float16)w1[i];
  for (int i = tid0; i < NVP * NK; i += stride) {
    const int r = i >> 10;
    pw2[i] = (_Float16)((r < NV) ? w2[i] : 0.f);
  }
  for (int i = tid0; i < 2 * NH; i += stride) pb1[i] = b1[i];
  for (int i = tid0; i < NVP; i += stride) pb2[i] = (i < NV) ? b2[i] : 0.f;
}

// ---------------- visual GEMV ----------------
__global__ void k_gemv512(const float* __restrict__ x, const float* __restrict__ w,
                          const float* __restrict__ bias, float* __restrict__ out) {
  const int b = blockIdx.x;
  __shared__ float xs[NH];
  for (int i = threadIdx.x; i < NH; i += 256) xs[i] = x[(size_t)b * NH + i];
  __syncthreads();
  const int wave = threadIdx.x >> 6, lane = threadIdx.x & 63;
  for (int j = wave; j < NH; j += 4) {
    const float* wr = w + (size_t)j * NH;
    float s = 0.f;
#pragma unroll
    for (int i = 0; i < 8; ++i) s += wr[lane + i * 64] * xs[lane + i * 64];
#pragma unroll
    for (int o = 32; o > 0; o >>= 1) s += __shfl_down(s, o);
    if (lane == 0) out[(size_t)b * NH + j] = s + bias[j];
  }
}

// second visual GEMV -> h0 (fp16)
__global__ void k_gemv2_h0(const float* __restrict__ feat1, const float* __restrict__ w,
                           const float* __restrict__ bias, _Float16* __restrict__ h0b) {
  const int b = blockIdx.x;
  __shared__ float xs[NH];
  for (int i = threadIdx.x; i < NH; i += 256) xs[i] = feat1[(size_t)b * NH + i];
  __syncthreads();
  const int wave = threadIdx.x >> 6, lane = threadIdx.x & 63;
  for (int j = wave; j < NH; j += 4) {
    const float* wr = w + (size_t)j * NH;
    float s = 0.f;
#pragma unroll
    for (int i = 0; i < 8; ++i) s += wr[lane + i * 64] * xs[lane + i * 64];
#pragma unroll
    for (int o = 32; o > 0; o >>= 1) s += __shfl_down(s, o);
    if (lane == 0) h0b[(size_t)b * NH + j] = (_Float16)(s + bias[j]);
  }
}

// ---------------- persistent LSTM chain (split-K pipeline) ----------------
// 256 blocks x 512 threads. bm = bid>>5 (32-row batch group of 32 blocks),
// bn = (j&7)*4+(j>>3) (64 permuted gate rows = 16 hidden units; XCD-local W).
// Per chain stage s: staged A = output of cell s-1 (32x512 fp16, coherent).
// Waves 0-3: x-GEMM (W_ih[l_s], K=512) -> gl. Waves 4-7: h-GEMM for cell s+2
// (W_hh[l_{s+2}], K=512, same A!) -> pend ring. Cell: gl + pend[l] + bias.
// Publish: 1KB h tile via wave0 wide volatile stores, vmcnt(0), flag; 32-flag poll.
__global__ __launch_bounds__(512) void k_lstm(const _Float16* __restrict__ Wih,
                                              const _Float16* __restrict__ Whh,
                                              const float* __restrict__ bias,
                                              _Float16* hx, const _Float16* __restrict__ h0b,
                                              const _Float16* __restrict__ x0,
                                              _Float16* __restrict__ outs,
                                              const int* __restrict__ rowmap, const int* __restrict__ colmap,
                                              int* flags) {
  const int tid = threadIdx.x;
  const int lane = tid & 63;
  const int wave = tid >> 6;
  const int bid = blockIdx.x;
  const int j = bid & 31;
  const int bm = bid >> 5;
  const int bn = (j & 7) * 4 + (j >> 3);
  const int gbase = bm * 32;
  const int grp = wave >> 2;   // 0: x-GEMM, 1: h-GEMM
  const int wn = wave & 3;     // 16-gate-row slice within block's 64
  const int lr = lane & 15;
  const int lh = lane >> 4;
  const int nb0 = bn * 64 + wn * 16;
  __shared__ _Float16 Als[32][536];      // staged A; 268 dw stride (≡12 mod 32: 2-way, free)
  __shared__ float gl[32][65];           // x-part gates (65 dw: conflict-free cell reads)
  __shared__ float pend[3][32][65];      // pending h-part gates ring
  __shared__ _Float16 hout[32][16];      // gathered h tile for wide publish

  int rm[4], cm[4];
#pragma unroll
  for (int r = 0; r < 4; ++r) {
    rm[r] = rowmap[lane * 4 + r];
    cm[r] = colmap[lane * 4 + r];
  }
  const int bl_ = tid >> 4;              // cell ownership: batch row
  const int hu = tid & 15;               // hidden unit
  float creg[NL] = {0.f, 0.f, 0.f};
  float bsv[NL][4];
#pragma unroll
  for (int l = 0; l < NL; ++l)
#pragma unroll
    for (int g = 0; g < 4; ++g) bsv[l][g] = bias[l * NG + (bn * 16 + hu) * 4 + g];

#define STAGE_A(SRCBASE)                                              \
  do {                                                                \
    const _Float16* _sb = (SRCBASE);                                  \
    _Pragma("unroll") for (int c = 0; c < 4; ++c) {                   \
      const int i_ = tid + c * 512;                                   \
      const int r_ = i_ >> 6;                                         \
      const int cc_ = i_ & 63;                                        \
      u32x4 v_ = *(const volatile u32x4*)(_sb + (size_t)r_ * NH + cc_ * 8); \
      *(u32x4*)&Als[r_][cc_ * 8] = v_;                                \
    }                                                                 \
  } while (0)

  // ---- prologue: pend[l] = h0 @ Whh[l]^T for the three t=0 cells ----
  STAGE_A(h0b + (size_t)(bm * 32) * NH);
  __syncthreads();
  if (grp == 0) {
#pragma unroll 1
    for (int lp = 0; lp < 3; ++lp) {
      const _Float16* bp = Whh + ((size_t)(lp * NG + nb0 + lr)) * NH + lh * 8;
      f32x4 a0 = {0.f, 0.f, 0.f, 0.f}, a1 = {0.f, 0.f, 0.f, 0.f};
#pragma unroll 4
      for (int kk = 0; kk < 16; ++kk) {
        f16x8 av0 = *(const f16x8*)&Als[lr][kk * 32 + lh * 8];
        f16x8 av1 = *(const f16x8*)&Als[16 + lr][kk * 32 + lh * 8];
        f16x8 bv = *(const f16x8*)(bp + (size_t)kk * 32);
        a0 = __builtin_amdgcn_mfma_f32_16x16x32_f16(av0, bv, a0, 0, 0, 0);
        a1 = __builtin_amdgcn_mfma_f32_16x16x32_f16(av1, bv, a1, 0, 0, 0);
      }
#pragma unroll
      for (int r = 0; r < 4; ++r) {
        pend[lp][rm[r]][wn * 16 + cm[r]] = a0[r];
        pend[lp][16 + rm[r]][wn * 16 + cm[r]] = a1[r];
      }
    }
  }
  __syncthreads();
  STAGE_A(x0 + (size_t)(bm * 32) * NH);  // A for s=0
  __syncthreads();

  // ---- main chain ----
#pragma unroll 1
  for (int t = 0; t < NT; ++t) {
#pragma unroll
    for (int l = 0; l < NL; ++l) {
      const int s = t * 3 + l;
      if (grp == 0) {
        // critical x-GEMM: gates_x(cell s) = A @ Wih[l]^T
        const _Float16* bp = Wih + ((size_t)(l * NG + nb0 + lr)) * NH + lh * 8;
        f32x4 a0 = {0.f, 0.f, 0.f, 0.f}, a1 = {0.f, 0.f, 0.f, 0.f};
#pragma unroll 4
        for (int kk = 0; kk < 16; ++kk) {
          f16x8 av0 = *(const f16x8*)&Als[lr][kk * 32 + lh * 8];
          f16x8 av1 = *(const f16x8*)&Als[16 + lr][kk * 32 + lh * 8];
          f16x8 bv = *(const f16x8*)(bp + (size_t)kk * 32);
          a0 = __builtin_amdgcn_mfma_f32_16x16x32_f16(av0, bv, a0, 0, 0, 0);
          a1 = __builtin_amdgcn_mfma_f32_16x16x32_f16(av1, bv, a1, 0, 0, 0);
        }
#pragma unroll
        for (int r = 0; r < 4; ++r) {
          gl[rm[r]][wn * 16 + cm[r]] = a0[r];
          gl[16 + rm[r]][wn * 16 + cm[r]] = a1[r];
        }
      } else if (s >= 1 && s <= NS - 3) {
        // off-path h-GEMM for cell s+2: same A, W_hh[(l+2)%3]
        const int l2 = (l == 0) ? 2 : l - 1;
        const _Float16* bp = Whh + ((size_t)(l2 * NG + nb0 + lr)) * NH + lh * 8;
        f32x4 a0 = {0.f, 0.f, 0.f, 0.f}, a1 = {0.f, 0.f, 0.f, 0.f};
#pragma unroll 4
        for (int kk = 0; kk < 16; ++kk) {
          f16x8 av0 = *(const f16x8*)&Als[lr][kk * 32 + lh * 8];
          f16x8 av1 = *(const f16x8*)&Als[16 + lr][kk * 32 + lh * 8];
          f16x8 bv = *(const f16x8*)(bp + (size_t)kk * 32);
          a0 = __builtin_amdgcn_mfma_f32_16x16x32_f16(av0, bv, a0, 0, 0, 0);
          a1 = __builtin_amdgcn_mfma_f32_16x16x32_f16(av1, bv, a1, 0, 0, 0);
        }
#pragma unroll
        for (int r = 0; r < 4; ++r) {
          pend[l2][rm[r]][wn * 16 + cm[r]] = a0[r];
          pend[l2][16 + rm[r]][wn * 16 + cm[r]] = a1[r];
        }
      }
      __syncthreads();
      // cell update: gates = gl + pend[l] + bias
      {
        const float gi = gl[bl_][hu * 4 + 0] + pend[l][bl_][hu * 4 + 0] + bsv[l][0];
        const float gf = gl[bl_][hu * 4 + 1] + pend[l][bl_][hu * 4 + 1] + bsv[l][1];
        const float gg = gl[bl_][hu * 4 + 2] + pend[l][bl_][hu * 4 + 2] + bsv[l][2];
        const float go = gl[bl_][hu * 4 + 3] + pend[l][bl_][hu * 4 + 3] + bsv[l][3];
        const float cn = sigf(gf) * creg[l] + sigf(gi) * tanhf_(gg);
        const float hn = sigf(go) * tanhf_(cn);
        creg[l] = cn;
        hout[bl_][hu] = (_Float16)hn;
      }
      __syncthreads();
      // publish h (wave0, wide volatile) + outs (wave1, l==2) + flag
      if (wave == 0) {
        const int row = lane >> 1, half = lane & 1;
        _Float16* dst = hx + (size_t)(s & 1) * NB * NH + (size_t)(bm * 32 + row) * NH + bn * 16 + half * 8;
        u32x4 v = *(const u32x4*)&hout[row][half * 8];
        *(volatile u32x4*)dst = v;
        asm volatile("s_waitcnt vmcnt(0)" ::: "memory");
        if (lane == 0) *(volatile int*)&flags[(gbase + j) * 16] = s + 1;
      }
      if (wave == 1 && l == 2) {
        const int row = lane >> 1, half = lane & 1;
        _Float16* dst = outs + ((size_t)t * NB + bm * 32 + row) * NH + bn * 16 + half * 8;
        *(u32x4*)dst = *(const u32x4*)&hout[row][half * 8];
      }
      if (s < NS - 1) {
        if (tid < 32) {
          const volatile int* fp = (const volatile int*)&flags[(gbase + tid) * 16];
          while (*fp < s + 1) __builtin_amdgcn_s_sleep(1);
        }
        __syncthreads();
        STAGE_A(hx + (size_t)(s & 1) * NB * NH + (size_t)(bm * 32) * NH);
        __syncthreads();
      }
    }
  }
#undef STAGE_A
}

// ---------------- projection head: gelu(res@W1^T+b1)@W2^T+b2 -> out[b][v][t] (f32) ----------------
__global__ __launch_bounds__(256) void k_proj(const _Float16* __restrict__ outs, const _Float16* __restrict__ pw1,
                                              const float* __restrict__ pb1, const _Float16* __restrict__ pw2,
                                              const float* __restrict__ pb2,
                                              const int* __restrict__ rowmap, const int* __restrict__ colmap,
                                              float* __restrict__ out) {
  const int tid = threadIdx.x;
  const int lane = tid & 63;
  const int wave = tid >> 6;
  const int lr = lane & 15;
  const int lh = lane >> 4;
  const int mbase = blockIdx.x * 16;
  __shared__ _Float16 hm[16][NK + 8];
  int rm[4], cm[4];
#pragma unroll
  for (int r = 0; r < 4; ++r) {
    rm[r] = rowmap[lane * 4 + r];
    cm[r] = colmap[lane * 4 + r];
  }
  const int mrow = mbase + lr;
  const _Float16* ap = outs + ((size_t)(mrow % NT) * NB + (mrow / NT)) * NH + lh * 8;
  for (int nf = 0; nf < 16; ++nf) {
    const int n0 = wave * 256 + nf * 16;
    f32x4 acc = {0.f, 0.f, 0.f, 0.f};
    const _Float16* bp = pw1 + (size_t)(n0 + lr) * NH + lh * 8;
#pragma unroll 4
    for (int kk = 0; kk < 16; ++kk) {
      f16x8 a = *(const f16x8*)(ap + kk * 32);
      f16x8 b = *(const f16x8*)(bp + kk * 32);
      acc = __builtin_amdgcn_mfma_f32_16x16x32_f16(a, b, acc, 0, 0, 0);
    }
#pragma unroll
    for (int r = 0; r < 4; ++r) {
      const float v = acc[r] + pb1[n0 + cm[r]];
      const float gv = 0.5f * v * (1.f + erff(v * 0.70710678118654752f));
      hm[rm[r]][n0 + cm[r]] = (_Float16)gv;
    }
  }
  __syncthreads();
  for (int nf = wave; nf < 7; nf += 4) {
    const int n0 = nf * 16;
    f32x4 acc = {0.f, 0.f, 0.f, 0.f};
    const _Float16* bp = pw2 + (size_t)(n0 + lr) * NK + lh * 8;
#pragma unroll 4
    for (int kk = 0; kk < 32; ++kk) {
      f16x8 a = *(const f16x8*)(&hm[lr][kk * 32 + lh * 8]);
      f16x8 b = *(const f16x8*)(bp + kk * 32);
      acc = __builtin_amdgcn_mfma_f32_16x16x32_f16(a, b, acc, 0, 0, 0);
    }
#pragma unroll
    for (int r = 0; r < 4; ++r) {
      const int v = n0 + cm[r];
      if (v < NV) {
        const int m = mbase + rm[r];
        out[((size_t)(m / NT) * NV + v) * NT + (m % NT)] = acc[r] + pb2[v];
      }
    }
  }
}

extern "C" void kernel_launch(void* const* d_in, const int* in_sizes, int n_in,
                              void* d_out, int out_size, void* d_ws, size_t ws_size,
                              hipStream_t stream) {
  const float* feat = (const float*)d_in[0];
  const float* visual_w = (const float*)d_in[1];
  const float* visual_b = (const float*)d_in[2];
  const float* embed = (const float*)d_in[3];
  const float* w_ih = (const float*)d_in[4];
  const float* w_hh = (const float*)d_in[5];
  const float* b_ih = (const float*)d_in[6];
  const float* b_hh = (const float*)d_in[7];
  const float* proj_w1 = (const float*)d_in[8];
  const float* proj_b1 = (const float*)d_in[9];
  const float* proj_w2 = (const float*)d_in[10];
  const float* proj_b2 = (const float*)d_in[11];
  const int* start_idx = (const int*)d_in[12];
  float* out = (float*)d_out;  // reference output dtype is float32

  char* ws = (char*)d_ws;
  size_t off = 0;
  auto alloc = [&](size_t bytes) -> void* {
    void* p = ws + off;
    off += (bytes + 255) & ~(size_t)255;
    return p;
  };
  _Float16* Wih = (_Float16*)alloc((size_t)NL * NG * NH * 2);
  _Float16* Whh = (_Float16*)alloc((size_t)NL * NG * NH * 2);
  float* bias = (float*)alloc((size_t)NL * NG * 4);
  _Float16* hx = (_Float16*)alloc((size_t)2 * NB * NH * 2);   // chain-output double buffer
  _Float16* h0b = (_Float16*)alloc((size_t)NB * NH * 2);
  _Float16* x0 = (_Float16*)alloc((size_t)NB * NH * 2);
  _Float16* outsb = (_Float16*)alloc((size_t)NT * NB * NH * 2);
  float* feat1 = (float*)alloc((size_t)NB * NH * 4);
  _Float16* pw1 = (_Float16*)alloc((size_t)2 * NH * NH * 2);
  _Float16* pw2 = (_Float16*)alloc((size_t)NVP * NK * 2);
  float* pb1 = (float*)alloc((size_t)2 * NH * 4);
  float* pb2 = (float*)alloc((size_t)NVP * 4);
  int* flags = (int*)alloc(256 * 16 * 4);
  int* rowmap = (int*)alloc(256 * 4);
  int* colmap = (int*)alloc(256 * 4);
  if (off > ws_size) return;  // insufficient workspace — fail visibly

  k_probe<<<dim3(1), dim3(64), 0, stream>>>(rowmap, colmap);
  k_prep_w<<<dim3(2048), dim3(256), 0, stream>>>(w_ih, w_hh, b_ih, b_hh, Wih, Whh, bias);
  k_prep_misc<<<dim3(1024), dim3(256), 0, stream>>>(embed, start_idx, proj_w1, proj_b1, proj_w2, proj_b2,
                                                    x0, pw1, pb1, pw2, pb2, flags);
  k_gemv512<<<dim3(NB), dim3(256), 0, stream>>>(feat, visual_w, visual_b, feat1);
  k_gemv2_h0<<<dim3(NB), dim3(256), 0, stream>>>(feat1, visual_w, visual_b, h0b);
  k_lstm<<<dim3(256), dim3(512), 0, stream>>>(Wih, Whh, bias, hx, h0b, x0, outsb, rowmap, colmap, flags);
  k_proj<<<dim3(3200), dim3(256), 0, stream>>>(outsb, pw1, pb1, pw2, pb2, rowmap, colmap, out);
}